// Round 2
// baseline (624.847 us; speedup 1.0000x reference)
//
#include <hip/hip_runtime.h>
#include <math.h>

#define B_ 2
#define T_ 4096
#define DM 1024
#define H_ 16
#define HDIM 64
#define FF_ 4096
#define M_ (B_*T_)    // 8192 tokens
#define NC_ 64        // scan chunks
#define LC_ 64        // chunk length

typedef short bf16x8 __attribute__((ext_vector_type(8)));
typedef float f32x4 __attribute__((ext_vector_type(4)));

__device__ __forceinline__ unsigned short f2bf(float f) {
  unsigned int u = __builtin_bit_cast(unsigned int, f);
  u += 0x7fffu + ((u >> 16) & 1u);
  return (unsigned short)(u >> 16);
}
__device__ __forceinline__ float bf2f(unsigned short h) {
  unsigned int u = ((unsigned int)h) << 16;
  return __builtin_bit_cast(float, u);
}
__device__ __forceinline__ void gload16(const void* g, void* l) {
  __builtin_amdgcn_global_load_lds(
      (const __attribute__((address_space(1))) unsigned int*)g,
      (__attribute__((address_space(3))) unsigned int*)l, 16, 0, 0);
}

// ---------------- weight f32 -> bf16 conversion (all 7 matrices, 1 launch) ----
struct CvtJob { const float* src; unsigned short* dst; int n4; };
struct CvtJobs { CvtJob j[7]; };

__global__ void cvt_all(CvtJobs jobs) {
  CvtJob jb = jobs.j[blockIdx.y];
  int i = blockIdx.x * 256 + threadIdx.x;   // float4 index
  if (i < jb.n4) {
    float4 v = ((const float4*)jb.src)[i];
    ushort4 o;
    o.x = f2bf(v.x); o.y = f2bf(v.y); o.z = f2bf(v.z); o.w = f2bf(v.w);
    ((ushort4*)jb.dst)[i] = o;
  }
}

// ---------------- per-row mean / rstd (C = 1024) ------------------------------
__global__ void row_stats(const float* __restrict__ X, float* __restrict__ st) {
  int row = blockIdx.x, tid = threadIdx.x;
  float4 v = *(const float4*)(X + (size_t)row * DM + tid * 4);
  float s = v.x + v.y + v.z + v.w;
  float ss = v.x*v.x + v.y*v.y + v.z*v.z + v.w*v.w;
#pragma unroll
  for (int off = 32; off; off >>= 1) { s += __shfl_down(s, off); ss += __shfl_down(ss, off); }
  __shared__ float sm[8];
  int wave = tid >> 6;
  if ((tid & 63) == 0) { sm[wave*2] = s; sm[wave*2+1] = ss; }
  __syncthreads();
  if (tid == 0) {
    float S = sm[0] + sm[2] + sm[4] + sm[6];
    float SS = sm[1] + sm[3] + sm[5] + sm[7];
    float mean = S * (1.f/DM);
    float var = SS * (1.f/DM) - mean*mean;
    st[row*2] = mean;
    st[row*2+1] = rsqrtf(var + 1e-5f);
  }
}

// ---------------- LN1 + depthwise causal conv, store xc as bf16 ---------------
__global__ void ln1_conv(const float* __restrict__ x, const float* __restrict__ st,
                         const float* __restrict__ lw, const float* __restrict__ lb,
                         const float* __restrict__ cw, const float* __restrict__ cb,
                         unsigned short* __restrict__ xc_b) {
  int row = blockIdx.x;              // b*T + t
  int t = row & (T_ - 1);
  int tid = threadIdx.x;
  int c0 = tid * 4;
  float4 w4 = *(const float4*)(lw + c0);
  float4 b4 = *(const float4*)(lb + c0);
  float4 cb4 = *(const float4*)(cb + c0);
  float a0 = cb4.x, a1 = cb4.y, a2 = cb4.z, a3 = cb4.w;
#pragma unroll
  for (int j = 0; j < 4; j++) {
    int tp = t - 3 + j;
    if (tp < 0) continue;
    int rp = row - 3 + j;
    float mean = st[rp*2], rstd = st[rp*2+1];
    float4 xv = *(const float4*)(x + (size_t)rp * DM + c0);
    float h0 = (xv.x - mean) * rstd * w4.x + b4.x;
    float h1 = (xv.y - mean) * rstd * w4.y + b4.y;
    float h2 = (xv.z - mean) * rstd * w4.z + b4.z;
    float h3 = (xv.w - mean) * rstd * w4.w + b4.w;
    a0 += h0 * cw[(c0+0)*4 + j];
    a1 += h1 * cw[(c0+1)*4 + j];
    a2 += h2 * cw[(c0+2)*4 + j];
    a3 += h3 * cw[(c0+3)*4 + j];
  }
  ushort4 o;
  o.x = f2bf(a0); o.y = f2bf(a1); o.z = f2bf(a2); o.w = f2bf(a3);
  *(ushort4*)(xc_b + (size_t)row * DM + c0) = o;
}

// ---------------- bf16 GEMM  C[M,N] = A[M,K] * Bw[N,K]^T ----------------------
// 128x128 tile, 4 waves (each 64x64 = 4x4 frags of 16x16x32), BK=32,
// global_load_lds width-16 staging (m97 structure).
// EPI: 0 = f32 store; 1 = sigmoid(acc+aux0[col]) f32; 2 = silu(acc) bf16;
//      3 = bf16 in-place: Cb[off] = bf16(bf2f(Cb[off])*acc);
//      4 = f32: Co[off] = aux0[off] + aux1[col]*acc
template<int EPI>
__global__ __launch_bounds__(256) void gemm_bt(
    const unsigned short* __restrict__ A, const unsigned short* __restrict__ Bw,
    float* __restrict__ Co, unsigned short* __restrict__ Cb,
    const float* __restrict__ aux0, const float* __restrict__ aux1,
    int M, int N, int K) {
  __shared__ unsigned short As[128 * 32];
  __shared__ unsigned short Bs[128 * 32];
  const int tid = threadIdx.x;
  const int lane = tid & 63, wave = tid >> 6;
  const int bm = blockIdx.x, bn = blockIdx.y;
  const int wr = wave >> 1, wc = wave & 1;
  const int srow = wave * 32 + (lane >> 2);   // staging row handled by this lane
  const int kb = (lane & 3) * 8;              // k-element offset (16B granule)
  unsigned short* As0 = &As[srow * 32 + kb];
  unsigned short* As1 = As0 + 16 * 32;
  unsigned short* Bs0 = &Bs[srow * 32 + kb];
  unsigned short* Bs1 = Bs0 + 16 * 32;
  const unsigned short* Ag0 = A + (size_t)(bm * 128 + srow) * K + kb;
  const unsigned short* Ag1 = Ag0 + (size_t)16 * K;
  const unsigned short* Bg0 = Bw + (size_t)(bn * 128 + srow) * K + kb;
  const unsigned short* Bg1 = Bg0 + (size_t)16 * K;

  f32x4 acc[4][4] = {};
  const int lrow = lane & 15;
  const int lk = (lane >> 4) * 8;

  for (int k0 = 0; k0 < K; k0 += 32) {
    gload16(Ag0, As0); gload16(Ag1, As1);
    gload16(Bg0, Bs0); gload16(Bg1, Bs1);
    Ag0 += 32; Ag1 += 32; Bg0 += 32; Bg1 += 32;
    __syncthreads();   // drains vmcnt (global_load_lds) + lgkm
    bf16x8 a[4], b[4];
#pragma unroll
    for (int i = 0; i < 4; i++) a[i] = *(const bf16x8*)&As[(wr*64 + i*16 + lrow)*32 + lk];
#pragma unroll
    for (int j = 0; j < 4; j++) b[j] = *(const bf16x8*)&Bs[(wc*64 + j*16 + lrow)*32 + lk];
#pragma unroll
    for (int i = 0; i < 4; i++)
#pragma unroll
      for (int j = 0; j < 4; j++)
        acc[i][j] = __builtin_amdgcn_mfma_f32_16x16x32_bf16(a[i], b[j], acc[i][j], 0, 0, 0);
    __syncthreads();
  }

  const int rg = (lane >> 4) * 4;
#pragma unroll
  for (int i = 0; i < 4; i++) {
    const int row0 = bm * 128 + wr * 64 + i * 16 + rg;
#pragma unroll
    for (int j = 0; j < 4; j++) {
      const int col = bn * 128 + wc * 64 + j * 16 + lrow;
#pragma unroll
      for (int r = 0; r < 4; r++) {
        float val = acc[i][j][r];
        size_t off = (size_t)(row0 + r) * N + col;
        if constexpr (EPI == 0) {
          Co[off] = val;
        } else if constexpr (EPI == 1) {
          Co[off] = 1.f / (1.f + __expf(-(val + aux0[col])));
        } else if constexpr (EPI == 2) {
          Cb[off] = f2bf(val / (1.f + __expf(-val)));
        } else if constexpr (EPI == 3) {
          Cb[off] = f2bf(bf2f(Cb[off]) * val);
        } else {
          Co[off] = aux0[off] + aux1[col] * val;
        }
      }
    }
  }
}

// ---------------- per-(token,head) k normalization, in place ------------------
__global__ void knorm(float* __restrict__ qk) {
  size_t i = (size_t)blockIdx.x * 4 + (threadIdx.x >> 6);  // token-head index
  int lane = threadIdx.x & 63;
  size_t base = i * HDIM + lane;
  float v = qk[base];
  float ss = v * v;
#pragma unroll
  for (int off = 32; off; off >>= 1) ss += __shfl_xor(ss, off);
  float n = fmaxf(sqrtf(ss), 1e-12f);
  qk[base] = v / n;
}

// ---- scan semantics (matches reference):
//   w[t]   = state[t] * gamma^t,  state[t] = v*g*(cos(t*freq) + k[t-1])
//   M[t]   = plain cumsum of w   (bounded: w decays with gamma^t)
//   memory = M[t] / (gamma^t + 1e-6)        [anti-decay: (1/gamma)^(t-s) weights]
//   out    = memory * k[t]
// ---------------- scan phase A: per-chunk sum of w -> carry -------------------
__global__ void scan_a(const float* __restrict__ v, const float* __restrict__ g,
                       const float* __restrict__ k, const float* __restrict__ ga,
                       float* __restrict__ carry) {
  int bid = blockIdx.x;                 // b*H*NC + h*NC + c
  int c = bid & (NC_ - 1);
  int h = (bid >> 6) & (H_ - 1);
  int b = bid >> 10;
  int d = threadIdx.x;                  // 64 threads
  double gamma = (double)ga[h];
  double freq = pow(10.0, (double)d * (1.0 / 63.0)) * (double)h;
  int t0 = c * LC_;
  size_t base = ((size_t)(b * T_ + t0)) * DM + h * HDIM + d;
  double p = pow(gamma, (double)t0);    // gamma^t
  double M = 0.0;
#pragma unroll 4
  for (int j = 0; j < LC_; j++) {
    int t = t0 + j;
    size_t idx = base + (size_t)j * DM;
    float kprev = (t > 0) ? k[idx - DM] : 0.f;
    double rev = ((double)t * freq) * 0.15915494309189535;   // angle / 2pi
    float fr = (float)(rev - floor(rev));
    float cs = __cosf(fr * 6.28318530717958647f);
    float s = v[idx] * g[idx] * (cs + kprev);
    M += (double)s * p;
    p *= gamma;
  }
  carry[(size_t)bid * HDIM + d] = (float)M;
}

// ---------------- scan phase B: plain exclusive prefix over chunk sums --------
__global__ void scan_b(float* __restrict__ carry) {
  int bh = blockIdx.x;                  // b*H + h
  int d = threadIdx.x;
  float M = 0.f;
  for (int c = 0; c < NC_; c++) {
    size_t idx = ((size_t)bh * NC_ + c) * HDIM + d;
    float t = carry[idx];
    carry[idx] = M;                     // exclusive: cumsum before chunk c
    M += t;
  }
}

// ---------------- scan phase C: replay with carry-in, write out (bf16) --------
__global__ void scan_c(const float* __restrict__ v, const float* __restrict__ g,
                       const float* __restrict__ k, const float* __restrict__ ga,
                       const float* __restrict__ carry, unsigned short* __restrict__ outb) {
  int bid = blockIdx.x;
  int c = bid & (NC_ - 1);
  int h = (bid >> 6) & (H_ - 1);
  int b = bid >> 10;
  int d = threadIdx.x;
  double gamma = (double)ga[h];
  double freq = pow(10.0, (double)d * (1.0 / 63.0)) * (double)h;
  int t0 = c * LC_;
  size_t base = ((size_t)(b * T_ + t0)) * DM + h * HDIM + d;
  double M = (double)carry[(size_t)bid * HDIM + d];
  double p = pow(gamma, (double)t0);    // gamma^t
#pragma unroll 4
  for (int j = 0; j < LC_; j++) {
    int t = t0 + j;
    size_t idx = base + (size_t)j * DM;
    float kprev = (t > 0) ? k[idx - DM] : 0.f;
    double rev = ((double)t * freq) * 0.15915494309189535;
    float fr = (float)(rev - floor(rev));
    float cs = __cosf(fr * 6.28318530717958647f);
    float s = v[idx] * g[idx] * (cs + kprev);
    M += (double)s * p;
    double mem = M / (p + 1e-6);
    outb[idx] = f2bf((float)mem * k[idx]);
    p *= gamma;
  }
}

// ---------------- residual 1: x1 = x + gamma1*LN(o_pre); also ln2 row stats ---
__global__ void resid_onorm(const float* __restrict__ x, const float* __restrict__ opre,
                            const float* __restrict__ ost, const float* __restrict__ onw,
                            const float* __restrict__ onb, const float* __restrict__ g1,
                            float* __restrict__ x1, float* __restrict__ st2) {
  int row = blockIdx.x, tid = threadIdx.x;
  float mean = ost[row*2], rstd = ost[row*2+1];
  size_t base = (size_t)row * DM + tid * 4;
  float4 o = *(const float4*)(opre + base);
  float4 xv = *(const float4*)(x + base);
  float4 w4 = *(const float4*)(onw + tid*4);
  float4 b4 = *(const float4*)(onb + tid*4);
  float4 gg = *(const float4*)(g1 + tid*4);
  float4 r;
  r.x = xv.x + gg.x * ((o.x - mean) * rstd * w4.x + b4.x);
  r.y = xv.y + gg.y * ((o.y - mean) * rstd * w4.y + b4.y);
  r.z = xv.z + gg.z * ((o.z - mean) * rstd * w4.z + b4.z);
  r.w = xv.w + gg.w * ((o.w - mean) * rstd * w4.w + b4.w);
  *(float4*)(x1 + base) = r;
  float s = r.x + r.y + r.z + r.w;
  float ss = r.x*r.x + r.y*r.y + r.z*r.z + r.w*r.w;
#pragma unroll
  for (int off = 32; off; off >>= 1) { s += __shfl_down(s, off); ss += __shfl_down(ss, off); }
  __shared__ float sm[8];
  int wave = tid >> 6;
  if ((tid & 63) == 0) { sm[wave*2] = s; sm[wave*2+1] = ss; }
  __syncthreads();
  if (tid == 0) {
    float S = sm[0] + sm[2] + sm[4] + sm[6];
    float SS = sm[1] + sm[3] + sm[5] + sm[7];
    float m2 = S * (1.f/DM);
    float var = SS * (1.f/DM) - m2*m2;
    st2[row*2] = m2;
    st2[row*2+1] = rsqrtf(var + 1e-5f);
  }
}

// ---------------- LN apply, store bf16 (h2 for MLP) ---------------------------
__global__ void ln_bf16(const float* __restrict__ in, const float* __restrict__ st,
                        const float* __restrict__ w, const float* __restrict__ b,
                        unsigned short* __restrict__ outb) {
  int row = blockIdx.x, tid = threadIdx.x;
  float mean = st[row*2], rstd = st[row*2+1];
  size_t base = (size_t)row * DM + tid * 4;
  float4 v = *(const float4*)(in + base);
  float4 w4 = *(const float4*)(w + tid*4);
  float4 b4 = *(const float4*)(b + tid*4);
  ushort4 o;
  o.x = f2bf((v.x - mean) * rstd * w4.x + b4.x);
  o.y = f2bf((v.y - mean) * rstd * w4.y + b4.y);
  o.z = f2bf((v.z - mean) * rstd * w4.z + b4.z);
  o.w = f2bf((v.w - mean) * rstd * w4.w + b4.w);
  *(ushort4*)(outb + base) = o;
}

// =============================================================================
extern "C" void kernel_launch(void* const* d_in, const int* in_sizes, int n_in,
                              void* d_out, int out_size, void* d_ws, size_t ws_size,
                              hipStream_t stream) {
  (void)in_sizes; (void)n_in; (void)out_size; (void)ws_size;
  const float* x      = (const float*)d_in[0];
  const float* ln1w   = (const float*)d_in[1];
  const float* ln1b   = (const float*)d_in[2];
  const float* convw  = (const float*)d_in[3];
  const float* convb  = (const float*)d_in[4];
  const float* qkw    = (const float*)d_in[5];
  const float* vw     = (const float*)d_in[6];
  const float* gw     = (const float*)d_in[7];
  const float* gb     = (const float*)d_in[8];
  const float* ow     = (const float*)d_in[9];
  const float* onw    = (const float*)d_in[10];
  const float* onb    = (const float*)d_in[11];
  const float* gattn  = (const float*)d_in[12];
  const float* ln2w   = (const float*)d_in[13];
  const float* ln2b   = (const float*)d_in[14];
  const float* gatew  = (const float*)d_in[15];
  const float* upw    = (const float*)d_in[16];
  const float* downw  = (const float*)d_in[17];
  const float* gamma1 = (const float*)d_in[18];
  const float* gamma2 = (const float*)d_in[19];
  float* out = (float*)d_out;

  // ---- workspace arena (peak ~146.5 MiB) ----
  char* ws = (char*)d_ws;
  const size_t MB = 1ull << 20;
  unsigned short* qkw_b   = (unsigned short*)(ws + 0);
  unsigned short* vw_b    = (unsigned short*)(ws + 2*MB);
  unsigned short* gw_b    = (unsigned short*)(ws + 4*MB);
  unsigned short* ow_b    = (unsigned short*)(ws + 6*MB);
  unsigned short* gatew_b = (unsigned short*)(ws + 8*MB);
  unsigned short* upw_b   = (unsigned short*)(ws + 16*MB);
  unsigned short* downw_b = (unsigned short*)(ws + 24*MB);
  unsigned short* xc_b    = (unsigned short*)(ws + 32*MB);  // [32,48) MiB
  float* qk    = (float*)(ws + 49*MB);                      // [49,81) -> k in place
  float* vbuf  = (float*)(ws + 81*MB);                      // [81,113)
  float* gbuf  = (float*)(ws + 113*MB);                     // [113,145)
  float* st1   = (float*)(ws + 145*MB);                     // 64 KiB
  float* st2   = (float*)(ws + 145*MB + 64*1024);           // 64 KiB
  float* carry = (float*)(ws + 146*MB);                     // 512 KiB
  // reuses (strictly after producers/consumers of the originals):
  unsigned short* out_b = xc_b;                              // [32,48)
  float* o_pre = vbuf;                                       // [81,113)
  float* x1    = (float*)(ws + 32*MB);                       // [32,64)
  unsigned short* h2_b  = (unsigned short*)(ws + 64*MB);     // [64,80)
  unsigned short* mlp_b = (unsigned short*)(ws + 81*MB);     // [81,145) 64 MiB

  // 1. weights -> bf16
  CvtJobs jobs = {{ {qkw,   qkw_b,   DM*DM/4},
                    {vw,    vw_b,    DM*DM/4},
                    {gw,    gw_b,    DM*DM/4},
                    {ow,    ow_b,    DM*DM/4},
                    {gatew, gatew_b, FF_*DM/4},
                    {upw,   upw_b,   FF_*DM/4},
                    {downw, downw_b, DM*FF_/4} }};
  cvt_all<<<dim3(4096, 7), 256, 0, stream>>>(jobs);

  // 2. LN1 stats + fused LN1+conv -> xc (bf16)
  row_stats<<<M_, 256, 0, stream>>>(x, st1);
  ln1_conv<<<M_, 256, 0, stream>>>(x, st1, ln1w, ln1b, convw, convb, xc_b);

  // 3. qk / v / g projections
  gemm_bt<0><<<dim3(64, 8), 256, 0, stream>>>(xc_b, qkw_b, qk,   nullptr, nullptr, nullptr, M_, DM, DM);
  gemm_bt<0><<<dim3(64, 8), 256, 0, stream>>>(xc_b, vw_b,  vbuf, nullptr, nullptr, nullptr, M_, DM, DM);
  gemm_bt<1><<<dim3(64, 8), 256, 0, stream>>>(xc_b, gw_b,  gbuf, nullptr, gb,      nullptr, M_, DM, DM);

  // 4. normalize k (in place in qk)
  knorm<<<M_ * H_ / 4, 256, 0, stream>>>(qk);

  // 5. chunked scan (real part only; Im is provably dead since q=k is real)
  scan_a<<<B_ * H_ * NC_, 64, 0, stream>>>(vbuf, gbuf, qk, gattn, carry);
  scan_b<<<B_ * H_, 64, 0, stream>>>(carry);
  scan_c<<<B_ * H_ * NC_, 64, 0, stream>>>(vbuf, gbuf, qk, gattn, carry, out_b);

  // 6. o projection + onorm + residual + ln2 stats + h2
  gemm_bt<0><<<dim3(64, 8), 256, 0, stream>>>(out_b, ow_b, o_pre, nullptr, nullptr, nullptr, M_, DM, DM);
  row_stats<<<M_, 256, 0, stream>>>(o_pre, st1);
  resid_onorm<<<M_, 256, 0, stream>>>(x, o_pre, st1, onw, onb, gamma1, x1, st2);
  ln_bf16<<<M_, 256, 0, stream>>>(x1, st2, ln2w, ln2b, h2_b);

  // 7. SwiGLU MLP: silu(h2@gateT) * (h2@upT) @ downT, fused epilogues
  gemm_bt<2><<<dim3(64, 32), 256, 0, stream>>>(h2_b, gatew_b, nullptr, mlp_b, nullptr, nullptr, M_, FF_, DM);
  gemm_bt<3><<<dim3(64, 32), 256, 0, stream>>>(h2_b, upw_b,   nullptr, mlp_b, nullptr, nullptr, M_, FF_, DM);
  gemm_bt<4><<<dim3(64, 8),  256, 0, stream>>>(mlp_b, downw_b, out, nullptr, x1, gamma2, M_, DM, FF_);
}

// Round 3
// 543.062 us; speedup vs baseline: 1.1506x; 1.1506x over previous
//
#include <hip/hip_runtime.h>
#include <math.h>

#define B_ 2
#define T_ 4096
#define DM 1024
#define H_ 16
#define HDIM 64
#define FF_ 4096
#define M_ (B_*T_)    // 8192 tokens
#define NC_ 64        // scan chunks
#define LC_ 64        // chunk length

typedef short bf16x8 __attribute__((ext_vector_type(8)));
typedef float f32x4 __attribute__((ext_vector_type(4)));

__device__ __forceinline__ unsigned short f2bf(float f) {
  unsigned int u = __builtin_bit_cast(unsigned int, f);
  u += 0x7fffu + ((u >> 16) & 1u);
  return (unsigned short)(u >> 16);
}
__device__ __forceinline__ void gload16(const void* g, void* l) {
  __builtin_amdgcn_global_load_lds(
      (const __attribute__((address_space(1))) unsigned int*)g,
      (__attribute__((address_space(3))) unsigned int*)l, 16, 0, 0);
}

// ---------------- weight f32 -> bf16 conversion (all 7 matrices, 1 launch) ----
struct CvtJob { const float* src; unsigned short* dst; int n4; };
struct CvtJobs { CvtJob j[7]; };

__global__ void cvt_all(CvtJobs jobs) {
  CvtJob jb = jobs.j[blockIdx.y];
  int i = blockIdx.x * 256 + threadIdx.x;   // float4 index
  if (i < jb.n4) {
    float4 v = ((const float4*)jb.src)[i];
    ushort4 o;
    o.x = f2bf(v.x); o.y = f2bf(v.y); o.z = f2bf(v.z); o.w = f2bf(v.w);
    ((ushort4*)jb.dst)[i] = o;
  }
}

// ---------------- gamma tables: p = gamma^t, ip = 1/(gamma^t + 1e-6) ----------
__global__ void gamma_tab(const float* __restrict__ ga, float2* __restrict__ tab) {
  int i = blockIdx.x * 256 + threadIdx.x;   // h*T + t  (65536)
  int h = i >> 12;
  int t = i & (T_ - 1);
  double g = (double)ga[h];
  double p = pow(g, (double)t);
  tab[i] = make_float2((float)p, (float)(1.0 / (p + 1e-6)));
}

// ---------------- per-row mean / rstd (C = 1024) ------------------------------
__global__ void row_stats(const float* __restrict__ X, float* __restrict__ st) {
  int row = blockIdx.x, tid = threadIdx.x;
  float4 v = *(const float4*)(X + (size_t)row * DM + tid * 4);
  float s = v.x + v.y + v.z + v.w;
  float ss = v.x*v.x + v.y*v.y + v.z*v.z + v.w*v.w;
#pragma unroll
  for (int off = 32; off; off >>= 1) { s += __shfl_down(s, off); ss += __shfl_down(ss, off); }
  __shared__ float sm[8];
  int wave = tid >> 6;
  if ((tid & 63) == 0) { sm[wave*2] = s; sm[wave*2+1] = ss; }
  __syncthreads();
  if (tid == 0) {
    float S = sm[0] + sm[2] + sm[4] + sm[6];
    float SS = sm[1] + sm[3] + sm[5] + sm[7];
    float mean = S * (1.f/DM);
    float var = SS * (1.f/DM) - mean*mean;
    st[row*2] = mean;
    st[row*2+1] = rsqrtf(var + 1e-5f);
  }
}

// ---------------- LN1 + depthwise causal conv, store xc as bf16 ---------------
__global__ void ln1_conv(const float* __restrict__ x, const float* __restrict__ st,
                         const float* __restrict__ lw, const float* __restrict__ lb,
                         const float* __restrict__ cw, const float* __restrict__ cb,
                         unsigned short* __restrict__ xc_b) {
  int row = blockIdx.x;              // b*T + t
  int t = row & (T_ - 1);
  int tid = threadIdx.x;
  int c0 = tid * 4;
  float4 w4 = *(const float4*)(lw + c0);
  float4 b4 = *(const float4*)(lb + c0);
  float4 cb4 = *(const float4*)(cb + c0);
  float a0 = cb4.x, a1 = cb4.y, a2 = cb4.z, a3 = cb4.w;
#pragma unroll
  for (int j = 0; j < 4; j++) {
    int tp = t - 3 + j;
    if (tp < 0) continue;
    int rp = row - 3 + j;
    float mean = st[rp*2], rstd = st[rp*2+1];
    float4 xv = *(const float4*)(x + (size_t)rp * DM + c0);
    float h0 = (xv.x - mean) * rstd * w4.x + b4.x;
    float h1 = (xv.y - mean) * rstd * w4.y + b4.y;
    float h2 = (xv.z - mean) * rstd * w4.z + b4.z;
    float h3 = (xv.w - mean) * rstd * w4.w + b4.w;
    a0 += h0 * cw[(c0+0)*4 + j];
    a1 += h1 * cw[(c0+1)*4 + j];
    a2 += h2 * cw[(c0+2)*4 + j];
    a3 += h3 * cw[(c0+3)*4 + j];
  }
  ushort4 o;
  o.x = f2bf(a0); o.y = f2bf(a1); o.z = f2bf(a2); o.w = f2bf(a3);
  *(ushort4*)(xc_b + (size_t)row * DM + c0) = o;
}

// ---------------- bf16 GEMM  C[M,N] = A[M,K] * Bw[N,K]^T ----------------------
// 128x128 tile, 4 waves (64x64 each = 4x4 frags of 16x16x32), BK=32,
// global_load_lds width-16 staging (m97 structure).
// EPI: 0 = f32 store to Co;
//      4 = f32: Co[off] = aux0[off] + aux1[col]*acc  (final residual)
//      5 = qkvg split (N=3072): col<1024 -> Co (qk), <2048 -> Co2 (v),
//          else Co3 = sigmoid(acc + aux1[lcol])  (g)
template<int EPI>
__global__ __launch_bounds__(256) void gemm_bt(
    const unsigned short* __restrict__ A, const unsigned short* __restrict__ Bw,
    float* __restrict__ Co, float* __restrict__ Co2, float* __restrict__ Co3,
    const float* __restrict__ aux0, const float* __restrict__ aux1,
    int M, int N, int K) {
  __shared__ unsigned short As[128 * 32];
  __shared__ unsigned short Bs[128 * 32];
  const int tid = threadIdx.x;
  const int lane = tid & 63, wave = tid >> 6;
  const int bm = blockIdx.x, bn = blockIdx.y;
  const int wr = wave >> 1, wc = wave & 1;
  const int srow = wave * 32 + (lane >> 2);
  const int kb = (lane & 3) * 8;
  unsigned short* As0 = &As[srow * 32 + kb];
  unsigned short* As1 = As0 + 16 * 32;
  unsigned short* Bs0 = &Bs[srow * 32 + kb];
  unsigned short* Bs1 = Bs0 + 16 * 32;
  const unsigned short* Ag0 = A + (size_t)(bm * 128 + srow) * K + kb;
  const unsigned short* Ag1 = Ag0 + (size_t)16 * K;
  const unsigned short* Bg0 = Bw + (size_t)(bn * 128 + srow) * K + kb;
  const unsigned short* Bg1 = Bg0 + (size_t)16 * K;

  f32x4 acc[4][4] = {};
  const int lrow = lane & 15;
  const int lk = (lane >> 4) * 8;

  for (int k0 = 0; k0 < K; k0 += 32) {
    gload16(Ag0, As0); gload16(Ag1, As1);
    gload16(Bg0, Bs0); gload16(Bg1, Bs1);
    Ag0 += 32; Ag1 += 32; Bg0 += 32; Bg1 += 32;
    __syncthreads();
    bf16x8 a[4], b[4];
#pragma unroll
    for (int i = 0; i < 4; i++) a[i] = *(const bf16x8*)&As[(wr*64 + i*16 + lrow)*32 + lk];
#pragma unroll
    for (int j = 0; j < 4; j++) b[j] = *(const bf16x8*)&Bs[(wc*64 + j*16 + lrow)*32 + lk];
#pragma unroll
    for (int i = 0; i < 4; i++)
#pragma unroll
      for (int j = 0; j < 4; j++)
        acc[i][j] = __builtin_amdgcn_mfma_f32_16x16x32_bf16(a[i], b[j], acc[i][j], 0, 0, 0);
    __syncthreads();
  }

  const int rg = (lane >> 4) * 4;
#pragma unroll
  for (int i = 0; i < 4; i++) {
    const int row0 = bm * 128 + wr * 64 + i * 16 + rg;
#pragma unroll
    for (int j = 0; j < 4; j++) {
      const int col = bn * 128 + wc * 64 + j * 16 + lrow;
#pragma unroll
      for (int r = 0; r < 4; r++) {
        float val = acc[i][j][r];
        if constexpr (EPI == 0) {
          Co[(size_t)(row0 + r) * N + col] = val;
        } else if constexpr (EPI == 4) {
          size_t off = (size_t)(row0 + r) * N + col;
          Co[off] = aux0[off] + aux1[col] * val;
        } else {  // EPI == 5
          int region = col >> 10, lcol = col & 1023;
          size_t off = (size_t)(row0 + r) * DM + lcol;
          if (region == 0)      Co[off]  = val;
          else if (region == 1) Co2[off] = val;
          else                  Co3[off] = 1.f / (1.f + __expf(-(val + aux1[lcol])));
        }
      }
    }
  }
}

// ---------------- fused gate+up GEMM: Cb = bf16( silu(A@Gw^T) * (A@Uw^T) ) ----
__global__ __launch_bounds__(256, 2) void gemm_gateup(
    const unsigned short* __restrict__ A, const unsigned short* __restrict__ Gw,
    const unsigned short* __restrict__ Uw, unsigned short* __restrict__ Cb,
    int M, int N, int K) {
  __shared__ unsigned short As[128 * 32];
  __shared__ unsigned short Gs[128 * 32];
  __shared__ unsigned short Us[128 * 32];
  const int tid = threadIdx.x;
  const int lane = tid & 63, wave = tid >> 6;
  const int bm = blockIdx.x, bn = blockIdx.y;
  const int wr = wave >> 1, wc = wave & 1;
  const int srow = wave * 32 + (lane >> 2);
  const int kb = (lane & 3) * 8;
  unsigned short* As0 = &As[srow * 32 + kb];   unsigned short* As1 = As0 + 16 * 32;
  unsigned short* Gs0 = &Gs[srow * 32 + kb];   unsigned short* Gs1 = Gs0 + 16 * 32;
  unsigned short* Us0 = &Us[srow * 32 + kb];   unsigned short* Us1 = Us0 + 16 * 32;
  const unsigned short* Ag0 = A  + (size_t)(bm * 128 + srow) * K + kb;
  const unsigned short* Ag1 = Ag0 + (size_t)16 * K;
  const unsigned short* Gg0 = Gw + (size_t)(bn * 128 + srow) * K + kb;
  const unsigned short* Gg1 = Gg0 + (size_t)16 * K;
  const unsigned short* Ug0 = Uw + (size_t)(bn * 128 + srow) * K + kb;
  const unsigned short* Ug1 = Ug0 + (size_t)16 * K;

  f32x4 ag[4][4] = {};
  f32x4 au[4][4] = {};
  const int lrow = lane & 15;
  const int lk = (lane >> 4) * 8;

  for (int k0 = 0; k0 < K; k0 += 32) {
    gload16(Ag0, As0); gload16(Ag1, As1);
    gload16(Gg0, Gs0); gload16(Gg1, Gs1);
    gload16(Ug0, Us0); gload16(Ug1, Us1);
    Ag0 += 32; Ag1 += 32; Gg0 += 32; Gg1 += 32; Ug0 += 32; Ug1 += 32;
    __syncthreads();
    bf16x8 a[4], bg[4], bu[4];
#pragma unroll
    for (int i = 0; i < 4; i++) a[i]  = *(const bf16x8*)&As[(wr*64 + i*16 + lrow)*32 + lk];
#pragma unroll
    for (int j = 0; j < 4; j++) bg[j] = *(const bf16x8*)&Gs[(wc*64 + j*16 + lrow)*32 + lk];
#pragma unroll
    for (int j = 0; j < 4; j++) bu[j] = *(const bf16x8*)&Us[(wc*64 + j*16 + lrow)*32 + lk];
#pragma unroll
    for (int i = 0; i < 4; i++)
#pragma unroll
      for (int j = 0; j < 4; j++) {
        ag[i][j] = __builtin_amdgcn_mfma_f32_16x16x32_bf16(a[i], bg[j], ag[i][j], 0, 0, 0);
        au[i][j] = __builtin_amdgcn_mfma_f32_16x16x32_bf16(a[i], bu[j], au[i][j], 0, 0, 0);
      }
    __syncthreads();
  }

  const int rg = (lane >> 4) * 4;
#pragma unroll
  for (int i = 0; i < 4; i++) {
    const int row0 = bm * 128 + wr * 64 + i * 16 + rg;
#pragma unroll
    for (int j = 0; j < 4; j++) {
      const int col = bn * 128 + wc * 64 + j * 16 + lrow;
#pragma unroll
      for (int r = 0; r < 4; r++) {
        float gv = ag[i][j][r];
        float uv = au[i][j][r];
        float w = (gv / (1.f + __expf(-gv))) * uv;
        Cb[(size_t)(row0 + r) * N + col] = f2bf(w);
      }
    }
  }
}

// ---------------- per-(token,head) k normalization, in place ------------------
__global__ void knorm(float* __restrict__ qk) {
  size_t i = (size_t)blockIdx.x * 4 + (threadIdx.x >> 6);
  int lane = threadIdx.x & 63;
  size_t base = i * HDIM + lane;
  float v = qk[base];
  float ss = v * v;
#pragma unroll
  for (int off = 32; off; off >>= 1) ss += __shfl_xor(ss, off);
  float n = fmaxf(sqrtf(ss), 1e-12f);
  qk[base] = v / n;
}

// ---- scan semantics (matches reference):
//   w[t]   = state[t] * gamma^t,  state[t] = v*g*(cos(t*freq) + k[t-1])
//   M[t]   = plain cumsum of w
//   memory = M[t] / (gamma^t + 1e-6);  out = memory * k[t]
// p and 1/(p+1e-6) come from the precomputed per-(h,t) table (all-float scan).
__global__ void scan_a(const float* __restrict__ v, const float* __restrict__ g,
                       const float* __restrict__ k, const float2* __restrict__ tab,
                       float* __restrict__ carry) {
  int bid = blockIdx.x;                 // b*H*NC + h*NC + c
  int c = bid & (NC_ - 1);
  int h = (bid >> 6) & (H_ - 1);
  int b = bid >> 10;
  int d = threadIdx.x;                  // 64 threads
  double freq = pow(10.0, (double)d * (1.0 / 63.0)) * (double)h;
  int t0 = c * LC_;
  size_t base = ((size_t)(b * T_ + t0)) * DM + h * HDIM + d;
  const float2* th = tab + (h << 12) + t0;
  float M = 0.f;
#pragma unroll 4
  for (int j = 0; j < LC_; j++) {
    int t = t0 + j;
    size_t idx = base + (size_t)j * DM;
    float kprev = (t > 0) ? k[idx - DM] : 0.f;
    double rev = ((double)t * freq) * 0.15915494309189535;   // angle / 2pi
    float fr = (float)(rev - floor(rev));
    float cs = __cosf(fr * 6.28318530717958647f);
    float s = v[idx] * g[idx] * (cs + kprev);
    M = fmaf(s, th[j].x, M);
  }
  carry[(size_t)bid * HDIM + d] = M;
}

__global__ void scan_b(float* __restrict__ carry) {
  int bh = blockIdx.x;                  // b*H + h
  int d = threadIdx.x;
  float M = 0.f;
  for (int c = 0; c < NC_; c++) {
    size_t idx = ((size_t)bh * NC_ + c) * HDIM + d;
    float t = carry[idx];
    carry[idx] = M;                     // exclusive prefix
    M += t;
  }
}

__global__ void scan_c(const float* __restrict__ v, const float* __restrict__ g,
                       const float* __restrict__ k, const float2* __restrict__ tab,
                       const float* __restrict__ carry, unsigned short* __restrict__ outb) {
  int bid = blockIdx.x;
  int c = bid & (NC_ - 1);
  int h = (bid >> 6) & (H_ - 1);
  int b = bid >> 10;
  int d = threadIdx.x;
  double freq = pow(10.0, (double)d * (1.0 / 63.0)) * (double)h;
  int t0 = c * LC_;
  size_t base = ((size_t)(b * T_ + t0)) * DM + h * HDIM + d;
  const float2* th = tab + (h << 12) + t0;
  float M = carry[(size_t)bid * HDIM + d];
#pragma unroll 4
  for (int j = 0; j < LC_; j++) {
    int t = t0 + j;
    size_t idx = base + (size_t)j * DM;
    float kprev = (t > 0) ? k[idx - DM] : 0.f;
    double rev = ((double)t * freq) * 0.15915494309189535;
    float fr = (float)(rev - floor(rev));
    float cs = __cosf(fr * 6.28318530717958647f);
    float s = v[idx] * g[idx] * (cs + kprev);
    float2 pt = th[j];
    M = fmaf(s, pt.x, M);
    outb[idx] = f2bf(M * pt.y * k[idx]);
  }
}

// ---------------- residual 1: x1 = x + gamma1*LN(o_pre); also ln2 row stats ---
__global__ void resid_onorm(const float* __restrict__ x, const float* __restrict__ opre,
                            const float* __restrict__ ost, const float* __restrict__ onw,
                            const float* __restrict__ onb, const float* __restrict__ g1,
                            float* __restrict__ x1, float* __restrict__ st2) {
  int row = blockIdx.x, tid = threadIdx.x;
  float mean = ost[row*2], rstd = ost[row*2+1];
  size_t base = (size_t)row * DM + tid * 4;
  float4 o = *(const float4*)(opre + base);
  float4 xv = *(const float4*)(x + base);
  float4 w4 = *(const float4*)(onw + tid*4);
  float4 b4 = *(const float4*)(onb + tid*4);
  float4 gg = *(const float4*)(g1 + tid*4);
  float4 r;
  r.x = xv.x + gg.x * ((o.x - mean) * rstd * w4.x + b4.x);
  r.y = xv.y + gg.y * ((o.y - mean) * rstd * w4.y + b4.y);
  r.z = xv.z + gg.z * ((o.z - mean) * rstd * w4.z + b4.z);
  r.w = xv.w + gg.w * ((o.w - mean) * rstd * w4.w + b4.w);
  *(float4*)(x1 + base) = r;
  float s = r.x + r.y + r.z + r.w;
  float ss = r.x*r.x + r.y*r.y + r.z*r.z + r.w*r.w;
#pragma unroll
  for (int off = 32; off; off >>= 1) { s += __shfl_down(s, off); ss += __shfl_down(ss, off); }
  __shared__ float sm[8];
  int wave = tid >> 6;
  if ((tid & 63) == 0) { sm[wave*2] = s; sm[wave*2+1] = ss; }
  __syncthreads();
  if (tid == 0) {
    float S = sm[0] + sm[2] + sm[4] + sm[6];
    float SS = sm[1] + sm[3] + sm[5] + sm[7];
    float m2 = S * (1.f/DM);
    float var = SS * (1.f/DM) - m2*m2;
    st2[row*2] = m2;
    st2[row*2+1] = rsqrtf(var + 1e-5f);
  }
}

// ---------------- LN apply, store bf16 (h2 for MLP) ---------------------------
__global__ void ln_bf16(const float* __restrict__ in, const float* __restrict__ st,
                        const float* __restrict__ w, const float* __restrict__ b,
                        unsigned short* __restrict__ outb) {
  int row = blockIdx.x, tid = threadIdx.x;
  float mean = st[row*2], rstd = st[row*2+1];
  size_t base = (size_t)row * DM + tid * 4;
  float4 v = *(const float4*)(in + base);
  float4 w4 = *(const float4*)(w + tid*4);
  float4 b4 = *(const float4*)(b + tid*4);
  ushort4 o;
  o.x = f2bf((v.x - mean) * rstd * w4.x + b4.x);
  o.y = f2bf((v.y - mean) * rstd * w4.y + b4.y);
  o.z = f2bf((v.z - mean) * rstd * w4.z + b4.z);
  o.w = f2bf((v.w - mean) * rstd * w4.w + b4.w);
  *(ushort4*)(outb + base) = o;
}

// =============================================================================
extern "C" void kernel_launch(void* const* d_in, const int* in_sizes, int n_in,
                              void* d_out, int out_size, void* d_ws, size_t ws_size,
                              hipStream_t stream) {
  (void)in_sizes; (void)n_in; (void)out_size; (void)ws_size;
  const float* x      = (const float*)d_in[0];
  const float* ln1w   = (const float*)d_in[1];
  const float* ln1b   = (const float*)d_in[2];
  const float* convw  = (const float*)d_in[3];
  const float* convb  = (const float*)d_in[4];
  const float* qkw    = (const float*)d_in[5];
  const float* vw     = (const float*)d_in[6];
  const float* gw     = (const float*)d_in[7];
  const float* gb     = (const float*)d_in[8];
  const float* ow     = (const float*)d_in[9];
  const float* onw    = (const float*)d_in[10];
  const float* onb    = (const float*)d_in[11];
  const float* gattn  = (const float*)d_in[12];
  const float* ln2w   = (const float*)d_in[13];
  const float* ln2b   = (const float*)d_in[14];
  const float* gatew  = (const float*)d_in[15];
  const float* upw    = (const float*)d_in[16];
  const float* downw  = (const float*)d_in[17];
  const float* gamma1 = (const float*)d_in[18];
  const float* gamma2 = (const float*)d_in[19];
  float* out = (float*)d_out;

  // ---- workspace arena (peak 146.5 MiB, same as passing R2) ----
  char* ws = (char*)d_ws;
  const size_t MB = 1ull << 20;
  unsigned short* qkvg_b  = (unsigned short*)(ws + 0);      // [0,6) qk|v|g concat
  unsigned short* ow_b    = (unsigned short*)(ws + 6*MB);
  unsigned short* gatew_b = (unsigned short*)(ws + 8*MB);
  unsigned short* upw_b   = (unsigned short*)(ws + 16*MB);
  unsigned short* downw_b = (unsigned short*)(ws + 24*MB);
  unsigned short* xc_b    = (unsigned short*)(ws + 32*MB);  // [32,48)
  float* qk    = (float*)(ws + 49*MB);                      // [49,81)
  float* vbuf  = (float*)(ws + 81*MB);                      // [81,113)
  float* gbuf  = (float*)(ws + 113*MB);                     // [113,145)
  float* st1   = (float*)(ws + 145*MB);                     // 64 KiB
  float* st2   = (float*)(ws + 145*MB + 64*1024);           // 64 KiB
  float2* tab  = (float2*)(ws + 145*MB + 128*1024);         // 512 KiB
  float* carry = (float*)(ws + 146*MB);                     // 512 KiB
  // reuses (stream-ordered after last consumer of the original):
  unsigned short* out_b = xc_b;                              // [32,48)
  float* o_pre = vbuf;                                       // [81,113)
  float* x1    = (float*)(ws + 32*MB);                       // [32,64)
  unsigned short* h2_b  = (unsigned short*)(ws + 64*MB);     // [64,80)
  unsigned short* mlp_b = (unsigned short*)(ws + 81*MB);     // [81,145)

  // 1. weights -> bf16 (qk/v/g contiguous -> one [3072,1024] B matrix)
  CvtJobs jobs = {{ {qkw,   qkvg_b,             DM*DM/4},
                    {vw,    qkvg_b + DM*DM,     DM*DM/4},
                    {gw,    qkvg_b + 2*DM*DM,   DM*DM/4},
                    {ow,    ow_b,               DM*DM/4},
                    {gatew, gatew_b,            FF_*DM/4},
                    {upw,   upw_b,              FF_*DM/4},
                    {downw, downw_b,            DM*FF_/4} }};
  cvt_all<<<dim3(4096, 7), 256, 0, stream>>>(jobs);
  gamma_tab<<<256, 256, 0, stream>>>(gattn, tab);

  // 2. LN1 stats + fused LN1+conv -> xc (bf16)
  row_stats<<<M_, 256, 0, stream>>>(x, st1);
  ln1_conv<<<M_, 256, 0, stream>>>(x, st1, ln1w, ln1b, convw, convb, xc_b);

  // 3. fused qk/v/g projection (N=3072, split epilogue)
  gemm_bt<5><<<dim3(64, 24), 256, 0, stream>>>(xc_b, qkvg_b, qk, vbuf, gbuf,
                                               nullptr, gb, M_, 3*DM, DM);

  // 4. normalize k (in place in qk)
  knorm<<<M_ * H_ / 4, 256, 0, stream>>>(qk);

  // 5. chunked scan (real part only; Im is dead since q=k is real)
  scan_a<<<B_ * H_ * NC_, 64, 0, stream>>>(vbuf, gbuf, qk, tab, carry);
  scan_b<<<B_ * H_, 64, 0, stream>>>(carry);
  scan_c<<<B_ * H_ * NC_, 64, 0, stream>>>(vbuf, gbuf, qk, tab, carry, out_b);

  // 6. o projection + onorm + residual + ln2 stats + h2
  gemm_bt<0><<<dim3(64, 8), 256, 0, stream>>>(out_b, ow_b, o_pre, nullptr, nullptr,
                                              nullptr, nullptr, M_, DM, DM);
  row_stats<<<M_, 256, 0, stream>>>(o_pre, st1);
  resid_onorm<<<M_, 256, 0, stream>>>(x, o_pre, st1, onw, onb, gamma1, x1, st2);
  ln_bf16<<<M_, 256, 0, stream>>>(x1, st2, ln2w, ln2b, h2_b);

  // 7. SwiGLU MLP: fused silu(h2@gateT)*(h2@upT) -> mlp_b, then down + residual
  gemm_gateup<<<dim3(64, 32), 256, 0, stream>>>(h2_b, gatew_b, upw_b, mlp_b, M_, FF_, DM);
  gemm_bt<4><<<dim3(64, 8), 256, 0, stream>>>(mlp_b, downw_b, out, nullptr, nullptr,
                                              x1, gamma2, M_, DM, FF_);
}

// Round 4
// 473.755 us; speedup vs baseline: 1.3189x; 1.1463x over previous
//
#include <hip/hip_runtime.h>
#include <math.h>

#define B_ 2
#define T_ 4096
#define DM 1024
#define H_ 16
#define HDIM 64
#define FF_ 4096
#define M_ (B_*T_)    // 8192 tokens
#define NC_ 64        // scan chunks
#define LC_ 64        // chunk length

typedef short bf16x8 __attribute__((ext_vector_type(8)));
typedef float f32x4 __attribute__((ext_vector_type(4)));

__device__ __forceinline__ unsigned short f2bf(float f) {
  unsigned int u = __builtin_bit_cast(unsigned int, f);
  u += 0x7fffu + ((u >> 16) & 1u);
  return (unsigned short)(u >> 16);
}
__device__ __forceinline__ float bf2f(unsigned short h) {
  unsigned int u = ((unsigned int)h) << 16;
  return __builtin_bit_cast(float, u);
}
__device__ __forceinline__ void gload16(const void* g, void* l) {
  __builtin_amdgcn_global_load_lds(
      (const __attribute__((address_space(1))) unsigned int*)g,
      (__attribute__((address_space(3))) unsigned int*)l, 16, 0, 0);
}

// ---------------- weight f32 -> bf16 conversion (all 7 matrices, 1 launch) ----
struct CvtJob { const float* src; unsigned short* dst; int n4; };
struct CvtJobs { CvtJob j[7]; };

__global__ void cvt_all(CvtJobs jobs) {
  CvtJob jb = jobs.j[blockIdx.y];
  int i = blockIdx.x * 256 + threadIdx.x;   // float4 index
  if (i < jb.n4) {
    float4 v = ((const float4*)jb.src)[i];
    ushort4 o;
    o.x = f2bf(v.x); o.y = f2bf(v.y); o.z = f2bf(v.z); o.w = f2bf(v.w);
    ((ushort4*)jb.dst)[i] = o;
  }
}

// ---------------- gamma tables: p = gamma^t, ip = 1/(gamma^t + 1e-6) ----------
__global__ void gamma_tab(const float* __restrict__ ga, float2* __restrict__ tab) {
  int i = blockIdx.x * 256 + threadIdx.x;   // h*T + t  (65536)
  int h = i >> 12;
  int t = i & (T_ - 1);
  double g = (double)ga[h];
  double p = pow(g, (double)t);
  tab[i] = make_float2((float)p, (float)(1.0 / (p + 1e-6)));
}

// ---------------- fused LN1-stats + LN1 + causal depthwise conv -> bf16 -------
// 16-token tile per block, sequential walk with 4-tap ring buffer; reads x ~1.2x.
#define CTI 16
__global__ void ln1_conv2(const float* __restrict__ x,
                          const float* __restrict__ lw, const float* __restrict__ lb,
                          const float* __restrict__ cw, const float* __restrict__ cb,
                          unsigned short* __restrict__ xcb) {
  int t0 = blockIdx.x * CTI;
  int tid = threadIdx.x, c0 = tid * 4;
  float4 w4 = *(const float4*)(lw + c0);
  float4 b4 = *(const float4*)(lb + c0);
  float4 cb4 = *(const float4*)(cb + c0);
  float4 cwA = *(const float4*)(cw + (c0+0)*4);
  float4 cwB = *(const float4*)(cw + (c0+1)*4);
  float4 cwC = *(const float4*)(cw + (c0+2)*4);
  float4 cwD = *(const float4*)(cw + (c0+3)*4);
  float4 hm3 = {0,0,0,0}, hm2 = {0,0,0,0}, hm1 = {0,0,0,0};
  __shared__ float sm[8];
  int warm = ((t0 & (T_ - 1)) != 0) ? 3 : 0;   // no warm-up at batch start (zero pad)
  int row = t0 - warm;
  float4 xv = *(const float4*)(x + (size_t)row * DM + c0);
  for (int it = -warm; it < CTI; ++it) {
    float4 cur = xv;
    if (it < CTI - 1) xv = *(const float4*)(x + (size_t)(row + 1) * DM + c0);
    float s = cur.x + cur.y + cur.z + cur.w;
    float ss = cur.x*cur.x + cur.y*cur.y + cur.z*cur.z + cur.w*cur.w;
#pragma unroll
    for (int off = 32; off; off >>= 1) { s += __shfl_down(s, off); ss += __shfl_down(ss, off); }
    if ((tid & 63) == 0) { sm[(tid>>6)*2] = s; sm[(tid>>6)*2+1] = ss; }
    __syncthreads();
    float S = sm[0]+sm[2]+sm[4]+sm[6], SS = sm[1]+sm[3]+sm[5]+sm[7];
    __syncthreads();
    float mean = S * (1.f/DM);
    float rstd = rsqrtf(SS * (1.f/DM) - mean*mean + 1e-5f);
    float4 h;
    h.x = (cur.x - mean) * rstd * w4.x + b4.x;
    h.y = (cur.y - mean) * rstd * w4.y + b4.y;
    h.z = (cur.z - mean) * rstd * w4.z + b4.z;
    h.w = (cur.w - mean) * rstd * w4.w + b4.w;
    if (it >= 0) {
      float o0 = cb4.x + hm3.x*cwA.x + hm2.x*cwA.y + hm1.x*cwA.z + h.x*cwA.w;
      float o1 = cb4.y + hm3.y*cwB.x + hm2.y*cwB.y + hm1.y*cwB.z + h.y*cwB.w;
      float o2 = cb4.z + hm3.z*cwC.x + hm2.z*cwC.y + hm1.z*cwC.z + h.z*cwC.w;
      float o3 = cb4.w + hm3.w*cwD.x + hm2.w*cwD.y + hm1.w*cwD.z + h.w*cwD.w;
      ushort4 o;
      o.x = f2bf(o0); o.y = f2bf(o1); o.z = f2bf(o2); o.w = f2bf(o3);
      *(ushort4*)(xcb + (size_t)row * DM + c0) = o;
    }
    hm3 = hm2; hm2 = hm1; hm1 = h;
    row++;
  }
}

// ---------------- bf16 GEMM  C[M,N] = A[M,K] * Bw[N,K]^T ----------------------
// 128x128 tile, 4 waves, BK=32, global_load_lds width-16 (m97 structure).
// EPI: 0 = f32 store to Co;
//      4 = f32: Co[off] = aux0[off] + aux1[col]*acc  (final residual)
//      5 = qkvg bf16 split (N=3072, region uniform per block: bn>>3):
//          region0 -> Ck = bf16(k / max(||k||_head, 1e-12))   (knorm fused)
//          region1 -> Cv = bf16(acc)
//          region2 -> Cg = bf16(sigmoid(acc + aux1[lcol]))
template<int EPI>
__global__ __launch_bounds__(256) void gemm_bt(
    const unsigned short* __restrict__ A, const unsigned short* __restrict__ Bw,
    float* __restrict__ Co, unsigned short* __restrict__ Ck,
    unsigned short* __restrict__ Cv, unsigned short* __restrict__ Cg,
    const float* __restrict__ aux0, const float* __restrict__ aux1,
    int M, int N, int K) {
  __shared__ unsigned short As[128 * 32];
  __shared__ unsigned short Bs[128 * 32];
  const int tid = threadIdx.x;
  const int lane = tid & 63, wave = tid >> 6;
  const int bm = blockIdx.x, bn = blockIdx.y;
  const int wr = wave >> 1, wc = wave & 1;
  const int srow = wave * 32 + (lane >> 2);
  const int kb = (lane & 3) * 8;
  unsigned short* As0 = &As[srow * 32 + kb];
  unsigned short* As1 = As0 + 16 * 32;
  unsigned short* Bs0 = &Bs[srow * 32 + kb];
  unsigned short* Bs1 = Bs0 + 16 * 32;
  const unsigned short* Ag0 = A + (size_t)(bm * 128 + srow) * K + kb;
  const unsigned short* Ag1 = Ag0 + (size_t)16 * K;
  const unsigned short* Bg0 = Bw + (size_t)(bn * 128 + srow) * K + kb;
  const unsigned short* Bg1 = Bg0 + (size_t)16 * K;

  f32x4 acc[4][4] = {};
  const int lrow = lane & 15;
  const int lk = (lane >> 4) * 8;

  for (int k0 = 0; k0 < K; k0 += 32) {
    gload16(Ag0, As0); gload16(Ag1, As1);
    gload16(Bg0, Bs0); gload16(Bg1, Bs1);
    Ag0 += 32; Ag1 += 32; Bg0 += 32; Bg1 += 32;
    __syncthreads();
    bf16x8 a[4], b[4];
#pragma unroll
    for (int i = 0; i < 4; i++) a[i] = *(const bf16x8*)&As[(wr*64 + i*16 + lrow)*32 + lk];
#pragma unroll
    for (int j = 0; j < 4; j++) b[j] = *(const bf16x8*)&Bs[(wc*64 + j*16 + lrow)*32 + lk];
#pragma unroll
    for (int i = 0; i < 4; i++)
#pragma unroll
      for (int j = 0; j < 4; j++)
        acc[i][j] = __builtin_amdgcn_mfma_f32_16x16x32_bf16(a[i], b[j], acc[i][j], 0, 0, 0);
    __syncthreads();
  }

  const int rg = (lane >> 4) * 4;
  if constexpr (EPI == 5) {
    const int region = bn >> 3;               // 1024-col regions, bn tiles aligned
#pragma unroll
    for (int i = 0; i < 4; i++) {
      const int row0 = bm * 128 + wr * 64 + i * 16 + rg;
#pragma unroll
      for (int r = 0; r < 4; r++) {
        const size_t rbase = (size_t)(row0 + r) * DM;
        if (region == 0) {
          float ss = 0.f;
#pragma unroll
          for (int j = 0; j < 4; j++) { float t = acc[i][j][r]; ss += t * t; }
#pragma unroll
          for (int off = 1; off < 16; off <<= 1) ss += __shfl_xor(ss, off);
          float rn = 1.f / fmaxf(sqrtf(ss), 1e-12f);
#pragma unroll
          for (int j = 0; j < 4; j++) {
            int lcol = bn * 128 + wc * 64 + j * 16 + lrow;
            Ck[rbase + lcol] = f2bf(acc[i][j][r] * rn);
          }
        } else if (region == 1) {
#pragma unroll
          for (int j = 0; j < 4; j++) {
            int lcol = (bn - 8) * 128 + wc * 64 + j * 16 + lrow;
            Cv[rbase + lcol] = f2bf(acc[i][j][r]);
          }
        } else {
#pragma unroll
          for (int j = 0; j < 4; j++) {
            int lcol = (bn - 16) * 128 + wc * 64 + j * 16 + lrow;
            float val = acc[i][j][r] + aux1[lcol];
            Cg[rbase + lcol] = f2bf(1.f / (1.f + __expf(-val)));
          }
        }
      }
    }
  } else {
#pragma unroll
    for (int i = 0; i < 4; i++) {
      const int row0 = bm * 128 + wr * 64 + i * 16 + rg;
#pragma unroll
      for (int j = 0; j < 4; j++) {
        const int col = bn * 128 + wc * 64 + j * 16 + lrow;
#pragma unroll
        for (int r = 0; r < 4; r++) {
          float val = acc[i][j][r];
          size_t off = (size_t)(row0 + r) * N + col;
          if constexpr (EPI == 0) {
            Co[off] = val;
          } else {  // EPI == 4
            Co[off] = aux0[off] + aux1[col] * val;
          }
        }
      }
    }
  }
}

// ---------------- fused gate+up GEMM: Cb = bf16( silu(A@Gw^T) * (A@Uw^T) ) ----
__global__ __launch_bounds__(256, 2) void gemm_gateup(
    const unsigned short* __restrict__ A, const unsigned short* __restrict__ Gw,
    const unsigned short* __restrict__ Uw, unsigned short* __restrict__ Cb,
    int M, int N, int K) {
  __shared__ unsigned short As[128 * 32];
  __shared__ unsigned short Gs[128 * 32];
  __shared__ unsigned short Us[128 * 32];
  const int tid = threadIdx.x;
  const int lane = tid & 63, wave = tid >> 6;
  const int bm = blockIdx.x, bn = blockIdx.y;
  const int wr = wave >> 1, wc = wave & 1;
  const int srow = wave * 32 + (lane >> 2);
  const int kb = (lane & 3) * 8;
  unsigned short* As0 = &As[srow * 32 + kb];   unsigned short* As1 = As0 + 16 * 32;
  unsigned short* Gs0 = &Gs[srow * 32 + kb];   unsigned short* Gs1 = Gs0 + 16 * 32;
  unsigned short* Us0 = &Us[srow * 32 + kb];   unsigned short* Us1 = Us0 + 16 * 32;
  const unsigned short* Ag0 = A  + (size_t)(bm * 128 + srow) * K + kb;
  const unsigned short* Ag1 = Ag0 + (size_t)16 * K;
  const unsigned short* Gg0 = Gw + (size_t)(bn * 128 + srow) * K + kb;
  const unsigned short* Gg1 = Gg0 + (size_t)16 * K;
  const unsigned short* Ug0 = Uw + (size_t)(bn * 128 + srow) * K + kb;
  const unsigned short* Ug1 = Ug0 + (size_t)16 * K;

  f32x4 ag[4][4] = {};
  f32x4 au[4][4] = {};
  const int lrow = lane & 15;
  const int lk = (lane >> 4) * 8;

  for (int k0 = 0; k0 < K; k0 += 32) {
    gload16(Ag0, As0); gload16(Ag1, As1);
    gload16(Gg0, Gs0); gload16(Gg1, Gs1);
    gload16(Ug0, Us0); gload16(Ug1, Us1);
    Ag0 += 32; Ag1 += 32; Gg0 += 32; Gg1 += 32; Ug0 += 32; Ug1 += 32;
    __syncthreads();
    bf16x8 a[4], bg[4], bu[4];
#pragma unroll
    for (int i = 0; i < 4; i++) a[i]  = *(const bf16x8*)&As[(wr*64 + i*16 + lrow)*32 + lk];
#pragma unroll
    for (int j = 0; j < 4; j++) bg[j] = *(const bf16x8*)&Gs[(wc*64 + j*16 + lrow)*32 + lk];
#pragma unroll
    for (int j = 0; j < 4; j++) bu[j] = *(const bf16x8*)&Us[(wc*64 + j*16 + lrow)*32 + lk];
#pragma unroll
    for (int i = 0; i < 4; i++)
#pragma unroll
      for (int j = 0; j < 4; j++) {
        ag[i][j] = __builtin_amdgcn_mfma_f32_16x16x32_bf16(a[i], bg[j], ag[i][j], 0, 0, 0);
        au[i][j] = __builtin_amdgcn_mfma_f32_16x16x32_bf16(a[i], bu[j], au[i][j], 0, 0, 0);
      }
    __syncthreads();
  }

  const int rg = (lane >> 4) * 4;
#pragma unroll
  for (int i = 0; i < 4; i++) {
    const int row0 = bm * 128 + wr * 64 + i * 16 + rg;
#pragma unroll
    for (int j = 0; j < 4; j++) {
      const int col = bn * 128 + wc * 64 + j * 16 + lrow;
#pragma unroll
      for (int r = 0; r < 4; r++) {
        float gv = ag[i][j][r];
        float uv = au[i][j][r];
        float w = (gv / (1.f + __expf(-gv))) * uv;
        Cb[(size_t)(row0 + r) * N + col] = f2bf(w);
      }
    }
  }
}

// ---- scan semantics (matches reference):
//   w[t]   = state[t] * gamma^t,  state[t] = v*g*(cos(t*freq) + k[t-1])
//   M[t]   = plain cumsum of w
//   memory = M[t] / (gamma^t + 1e-6);  out = memory * k[t]
// bf16 inputs; each lane owns 4 d-channels (ushort4 loads); 4 heads per block.
__global__ void scan_a(const unsigned short* __restrict__ kb,
                       const unsigned short* __restrict__ vb,
                       const unsigned short* __restrict__ gb,
                       const float2* __restrict__ tab, float* __restrict__ carry) {
  int bid = blockIdx.x;                 // ((b*4 + hg)*NC + c)
  int c = bid & (NC_ - 1);
  int hg = (bid >> 6) & 3;
  int b = bid >> 8;
  int L = threadIdx.x;
  int h = hg * 4 + (L >> 4);
  int d0 = (L & 15) * 4;
  double frq[4];
#pragma unroll
  for (int jj = 0; jj < 4; jj++)
    frq[jj] = pow(10.0, (double)(d0 + jj) * (1.0 / 63.0)) * (double)h;
  int t0 = c * LC_;
  size_t base = ((size_t)(b * T_ + t0)) * DM + h * HDIM + d0;
  const float2* th = tab + (h << 12) + t0;
  ushort4 kprev;
  if (t0 > 0) kprev = *(const ushort4*)(kb + base - DM);
  else { kprev.x = 0; kprev.y = 0; kprev.z = 0; kprev.w = 0; }
  float M0 = 0.f, M1 = 0.f, M2 = 0.f, M3 = 0.f;
#pragma unroll 4
  for (int j = 0; j < LC_; j++) {
    int t = t0 + j;
    size_t idx = base + (size_t)j * DM;
    ushort4 kc = *(const ushort4*)(kb + idx);
    ushort4 vv = *(const ushort4*)(vb + idx);
    ushort4 gg = *(const ushort4*)(gb + idx);
    float p = th[j].x;
    double td = (double)t;
    {
      double rev = td * frq[0] * 0.15915494309189535;
      float cs = __cosf((float)(rev - floor(rev)) * 6.28318530717958647f);
      M0 = fmaf(bf2f(vv.x) * bf2f(gg.x) * (cs + bf2f(kprev.x)), p, M0);
    }
    {
      double rev = td * frq[1] * 0.15915494309189535;
      float cs = __cosf((float)(rev - floor(rev)) * 6.28318530717958647f);
      M1 = fmaf(bf2f(vv.y) * bf2f(gg.y) * (cs + bf2f(kprev.y)), p, M1);
    }
    {
      double rev = td * frq[2] * 0.15915494309189535;
      float cs = __cosf((float)(rev - floor(rev)) * 6.28318530717958647f);
      M2 = fmaf(bf2f(vv.z) * bf2f(gg.z) * (cs + bf2f(kprev.z)), p, M2);
    }
    {
      double rev = td * frq[3] * 0.15915494309189535;
      float cs = __cosf((float)(rev - floor(rev)) * 6.28318530717958647f);
      M3 = fmaf(bf2f(vv.w) * bf2f(gg.w) * (cs + bf2f(kprev.w)), p, M3);
    }
    kprev = kc;
  }
  size_t cidx = (((size_t)(b * H_ + h)) * NC_ + c) * HDIM + d0;
  float4 o; o.x = M0; o.y = M1; o.z = M2; o.w = M3;
  *(float4*)(carry + cidx) = o;
}

__global__ void scan_b(float* __restrict__ carry) {
  int bh = blockIdx.x;                  // b*H + h
  int d = threadIdx.x;
  float M = 0.f;
  for (int c = 0; c < NC_; c++) {
    size_t idx = ((size_t)bh * NC_ + c) * HDIM + d;
    float t = carry[idx];
    carry[idx] = M;                     // exclusive prefix
    M += t;
  }
}

__global__ void scan_c(const unsigned short* __restrict__ kb,
                       const unsigned short* __restrict__ vb,
                       const unsigned short* __restrict__ gb,
                       const float2* __restrict__ tab, const float* __restrict__ carry,
                       unsigned short* __restrict__ outb) {
  int bid = blockIdx.x;
  int c = bid & (NC_ - 1);
  int hg = (bid >> 6) & 3;
  int b = bid >> 8;
  int L = threadIdx.x;
  int h = hg * 4 + (L >> 4);
  int d0 = (L & 15) * 4;
  double frq[4];
#pragma unroll
  for (int jj = 0; jj < 4; jj++)
    frq[jj] = pow(10.0, (double)(d0 + jj) * (1.0 / 63.0)) * (double)h;
  int t0 = c * LC_;
  size_t base = ((size_t)(b * T_ + t0)) * DM + h * HDIM + d0;
  const float2* th = tab + (h << 12) + t0;
  size_t cidx = (((size_t)(b * H_ + h)) * NC_ + c) * HDIM + d0;
  float4 Mi = *(const float4*)(carry + cidx);
  float M0 = Mi.x, M1 = Mi.y, M2 = Mi.z, M3 = Mi.w;
  ushort4 kprev;
  if (t0 > 0) kprev = *(const ushort4*)(kb + base - DM);
  else { kprev.x = 0; kprev.y = 0; kprev.z = 0; kprev.w = 0; }
#pragma unroll 4
  for (int j = 0; j < LC_; j++) {
    int t = t0 + j;
    size_t idx = base + (size_t)j * DM;
    ushort4 kc = *(const ushort4*)(kb + idx);
    ushort4 vv = *(const ushort4*)(vb + idx);
    ushort4 gg = *(const ushort4*)(gb + idx);
    float2 pt = th[j];
    double td = (double)t;
    ushort4 o;
    {
      double rev = td * frq[0] * 0.15915494309189535;
      float cs = __cosf((float)(rev - floor(rev)) * 6.28318530717958647f);
      M0 = fmaf(bf2f(vv.x) * bf2f(gg.x) * (cs + bf2f(kprev.x)), pt.x, M0);
      o.x = f2bf(M0 * pt.y * bf2f(kc.x));
    }
    {
      double rev = td * frq[1] * 0.15915494309189535;
      float cs = __cosf((float)(rev - floor(rev)) * 6.28318530717958647f);
      M1 = fmaf(bf2f(vv.y) * bf2f(gg.y) * (cs + bf2f(kprev.y)), pt.x, M1);
      o.y = f2bf(M1 * pt.y * bf2f(kc.y));
    }
    {
      double rev = td * frq[2] * 0.15915494309189535;
      float cs = __cosf((float)(rev - floor(rev)) * 6.28318530717958647f);
      M2 = fmaf(bf2f(vv.z) * bf2f(gg.z) * (cs + bf2f(kprev.z)), pt.x, M2);
      o.z = f2bf(M2 * pt.y * bf2f(kc.z));
    }
    {
      double rev = td * frq[3] * 0.15915494309189535;
      float cs = __cosf((float)(rev - floor(rev)) * 6.28318530717958647f);
      M3 = fmaf(bf2f(vv.w) * bf2f(gg.w) * (cs + bf2f(kprev.w)), pt.x, M3);
      o.w = f2bf(M3 * pt.y * bf2f(kc.w));
    }
    *(ushort4*)(outb + idx) = o;
    kprev = kc;
  }
}

// ---- fused: onorm stats + x1 = x + g1*LN(o_pre) (in place over o_pre) +
//      ln2 stats + h2 = bf16(LN2(x1))
__global__ void resid_fused(const float* __restrict__ x, float* xio,
                            const float* __restrict__ onw, const float* __restrict__ onb,
                            const float* __restrict__ g1,
                            const float* __restrict__ l2w, const float* __restrict__ l2b,
                            unsigned short* __restrict__ h2b) {
  int row = blockIdx.x, tid = threadIdx.x;
  size_t base = (size_t)row * DM + tid * 4;
  float4 o = *(const float4*)(xio + base);
  float4 xv = *(const float4*)(x + base);
  __shared__ float sm[8];
  // --- stats of o_pre ---
  float s = o.x + o.y + o.z + o.w;
  float ss = o.x*o.x + o.y*o.y + o.z*o.z + o.w*o.w;
#pragma unroll
  for (int off = 32; off; off >>= 1) { s += __shfl_down(s, off); ss += __shfl_down(ss, off); }
  if ((tid & 63) == 0) { sm[(tid>>6)*2] = s; sm[(tid>>6)*2+1] = ss; }
  __syncthreads();
  float S = sm[0]+sm[2]+sm[4]+sm[6], SS = sm[1]+sm[3]+sm[5]+sm[7];
  __syncthreads();
  float mean = S * (1.f/DM);
  float rstd = rsqrtf(SS * (1.f/DM) - mean*mean + 1e-5f);
  float4 w4 = *(const float4*)(onw + tid*4);
  float4 b4 = *(const float4*)(onb + tid*4);
  float4 gg = *(const float4*)(g1 + tid*4);
  float4 r;
  r.x = xv.x + gg.x * ((o.x - mean) * rstd * w4.x + b4.x);
  r.y = xv.y + gg.y * ((o.y - mean) * rstd * w4.y + b4.y);
  r.z = xv.z + gg.z * ((o.z - mean) * rstd * w4.z + b4.z);
  r.w = xv.w + gg.w * ((o.w - mean) * rstd * w4.w + b4.w);
  *(float4*)(xio + base) = r;
  // --- stats of x1 ---
  float s2 = r.x + r.y + r.z + r.w;
  float ss2 = r.x*r.x + r.y*r.y + r.z*r.z + r.w*r.w;
#pragma unroll
  for (int off = 32; off; off >>= 1) { s2 += __shfl_down(s2, off); ss2 += __shfl_down(ss2, off); }
  if ((tid & 63) == 0) { sm[(tid>>6)*2] = s2; sm[(tid>>6)*2+1] = ss2; }
  __syncthreads();
  float S2 = sm[0]+sm[2]+sm[4]+sm[6], SS2 = sm[1]+sm[3]+sm[5]+sm[7];
  float mean2 = S2 * (1.f/DM);
  float rstd2 = rsqrtf(SS2 * (1.f/DM) - mean2*mean2 + 1e-5f);
  float4 lw4 = *(const float4*)(l2w + tid*4);
  float4 lb4 = *(const float4*)(l2b + tid*4);
  ushort4 ho;
  ho.x = f2bf((r.x - mean2) * rstd2 * lw4.x + lb4.x);
  ho.y = f2bf((r.y - mean2) * rstd2 * lw4.y + lb4.y);
  ho.z = f2bf((r.z - mean2) * rstd2 * lw4.z + lb4.z);
  ho.w = f2bf((r.w - mean2) * rstd2 * lw4.w + lb4.w);
  *(ushort4*)(h2b + base) = ho;
}

// =============================================================================
extern "C" void kernel_launch(void* const* d_in, const int* in_sizes, int n_in,
                              void* d_out, int out_size, void* d_ws, size_t ws_size,
                              hipStream_t stream) {
  (void)in_sizes; (void)n_in; (void)out_size; (void)ws_size;
  const float* x      = (const float*)d_in[0];
  const float* ln1w   = (const float*)d_in[1];
  const float* ln1b   = (const float*)d_in[2];
  const float* convw  = (const float*)d_in[3];
  const float* convb  = (const float*)d_in[4];
  const float* qkw    = (const float*)d_in[5];
  const float* vw     = (const float*)d_in[6];
  const float* gw     = (const float*)d_in[7];
  const float* gb     = (const float*)d_in[8];
  const float* ow     = (const float*)d_in[9];
  const float* onw    = (const float*)d_in[10];
  const float* onb    = (const float*)d_in[11];
  const float* gattn  = (const float*)d_in[12];
  const float* ln2w   = (const float*)d_in[13];
  const float* ln2b   = (const float*)d_in[14];
  const float* gatew  = (const float*)d_in[15];
  const float* upw    = (const float*)d_in[16];
  const float* downw  = (const float*)d_in[17];
  const float* gamma1 = (const float*)d_in[18];
  const float* gamma2 = (const float*)d_in[19];
  float* out = (float*)d_out;

  // ---- workspace arena (peak 145.5 MiB; <= 147 MiB proven available) ----
  char* ws = (char*)d_ws;
  const size_t MB = 1ull << 20;
  unsigned short* qkvg_b  = (unsigned short*)(ws + 0);      // [0,6)
  unsigned short* ow_b    = (unsigned short*)(ws + 6*MB);   // [6,8)
  unsigned short* gatew_b = (unsigned short*)(ws + 8*MB);   // [8,16)
  unsigned short* upw_b   = (unsigned short*)(ws + 16*MB);  // [16,24)
  unsigned short* downw_b = (unsigned short*)(ws + 24*MB);  // [24,32)
  unsigned short* xc_b    = (unsigned short*)(ws + 32*MB);  // [32,48) bf16
  unsigned short* k_b     = (unsigned short*)(ws + 48*MB);  // [48,64) bf16
  unsigned short* v_b     = (unsigned short*)(ws + 64*MB);  // [64,80) bf16
  unsigned short* g_b     = (unsigned short*)(ws + 80*MB);  // [80,96) bf16
  float2* tab  = (float2*)(ws + 144*MB);                    // 512 KiB
  float* carry = (float*)(ws + 144*MB + 512*1024);          // 512 KiB
  // stream-ordered reuses:
  unsigned short* out_b = xc_b;                             // [32,48) after xc dead
  float* o_pre = (float*)(ws + 48*MB);                      // [48,80) after k,v dead
  float* x1    = o_pre;                                     // in-place in resid_fused
  unsigned short* h2_b  = (unsigned short*)(ws + 32*MB);    // [32,48) after o-proj
  unsigned short* mlp_b = (unsigned short*)(ws + 80*MB);    // [80,144) after g dead

  // 1. weights -> bf16 (qk/v/g contiguous -> one [3072,1024] B matrix)
  CvtJobs jobs = {{ {qkw,   qkvg_b,             DM*DM/4},
                    {vw,    qkvg_b + DM*DM,     DM*DM/4},
                    {gw,    qkvg_b + 2*DM*DM,   DM*DM/4},
                    {ow,    ow_b,               DM*DM/4},
                    {gatew, gatew_b,            FF_*DM/4},
                    {upw,   upw_b,              FF_*DM/4},
                    {downw, downw_b,            DM*FF_/4} }};
  cvt_all<<<dim3(4096, 7), 256, 0, stream>>>(jobs);
  gamma_tab<<<256, 256, 0, stream>>>(gattn, tab);

  // 2. fused LN1 stats + LN1 + conv -> xc (bf16)
  ln1_conv2<<<M_/CTI, 256, 0, stream>>>(x, ln1w, ln1b, convw, convb, xc_b);

  // 3. fused qk/v/g projection (N=3072) with knorm + sigmoid epilogues -> bf16
  gemm_bt<5><<<dim3(64, 24), 256, 0, stream>>>(xc_b, qkvg_b, nullptr, k_b, v_b, g_b,
                                               nullptr, gb, M_, 3*DM, DM);

  // 4. chunked scan (real part only; Im is dead since q=k is real)
  scan_a<<<B_ * (H_/4) * NC_, 64, 0, stream>>>(k_b, v_b, g_b, tab, carry);
  scan_b<<<B_ * H_, 64, 0, stream>>>(carry);
  scan_c<<<B_ * (H_/4) * NC_, 64, 0, stream>>>(k_b, v_b, g_b, tab, carry, out_b);

  // 5. o projection -> o_pre (f32), then fused onorm+resid+ln2 -> x1, h2
  gemm_bt<0><<<dim3(64, 8), 256, 0, stream>>>(out_b, ow_b, o_pre, nullptr, nullptr, nullptr,
                                              nullptr, nullptr, M_, DM, DM);
  resid_fused<<<M_, 256, 0, stream>>>(x, o_pre, onw, onb, gamma1, ln2w, ln2b, h2_b);

  // 6. SwiGLU MLP: fused silu(h2@gateT)*(h2@upT) -> mlp_b, then down + residual
  gemm_gateup<<<dim3(64, 32), 256, 0, stream>>>(h2_b, gatew_b, upw_b, mlp_b, M_, FF_, DM);
  gemm_bt<4><<<dim3(64, 8), 256, 0, stream>>>(mlp_b, downw_b, out, nullptr, nullptr, nullptr,
                                              x1, gamma2, M_, DM, FF_);
}